// Round 20
// baseline (104.378 us; speedup 1.0000x reference)
//
#include <hip/hip_runtime.h>

namespace {
constexpr int NB  = 131072;
constexpr int NJ  = 24;
constexpr int PAR[NJ] = {0,0,0,0,1,2,3,4,5,6,7,8,9,9,9,12,13,14,16,17,18,19,20,21};
constexpr int BLK = 128;        // 2 waves: wave0 = compute/stage, wave1 = store
constexpr int BPB = 64;         // batches per block (lane == batch)
constexpr int STR = 9;          // f4 stride per batch row in stage buffer
                                // (36 dwords -> start bank 4(t+c)%32: 2-way, free)
constexpr int NF4 = BPB * STR;  // 576 f4 per buffer; 2 buffers = 18432 B
}

typedef float f32x4 __attribute__((ext_vector_type(4)));

// Producer-consumer wave specialization. Champion (r8) couples stores behind
// loads in one in-order stream; here the compute wave (per-lane loads + chain
// + LDS stage) and store wave (LDS read + nt store) run decoupled, barriered
// per phase with lgkmcnt(0) ONLY — outstanding global loads (compute) and nt
// stores (store wave) are never drained at barriers. 14 phases: 12 x 2-joint
// oT + 2 x 12-joint oP. Phase p stages buf[p&1]; store reads p while compute
// stages p+1; buf[p%2] reuse at p+2 is safe (store's reads completed before
// its barrier p+1 via lgkmcnt). nt stores: +38% (r12 A/B).
__device__ __forceinline__ void sync_lds() {
    __builtin_amdgcn_sched_barrier(0);
    asm volatile("s_waitcnt lgkmcnt(0)" ::: "memory");
    __builtin_amdgcn_s_barrier();
    __builtin_amdgcn_sched_barrier(0);
}

__global__ __launch_bounds__(BLK, 4) void pose_kernel(
    const float* __restrict__ rot,
    const float* __restrict__ pos,
    float* __restrict__ outT,
    float* __restrict__ outP)
{
    __shared__ __align__(16) f32x4 lds[2 * NF4];
    const int t    = threadIdx.x;
    const int lane = t & 63;
    const int wv   = t >> 6;
    const int b0   = blockIdx.x * BPB;

    if (wv == 0) {
        // ================= compute wave =================
        const float* prow = pos + (size_t)(b0 + lane) * 72;
        const float* rrow = rot + (size_t)(b0 + lane) * 216;

        float Rg[NJ][9];
        float tg[NJ][3];
        float carry1[9];   // P of joints 5,6,7  (needed by group 1)
        float carry2[6];   // P of joints 13,14  (needed by group 2)

        #pragma unroll
        for (int g = 0; g < 3; ++g) {
            float Pg[24];
            #pragma unroll
            for (int i = 0; i < 6; ++i) {
                f32x4 v = *reinterpret_cast<const f32x4*>(prow + 24 * g + 4 * i);
                Pg[4*i+0] = v.x; Pg[4*i+1] = v.y; Pg[4*i+2] = v.z; Pg[4*i+3] = v.w;
            }

            #pragma unroll
            for (int q = 0; q < 2; ++q) {
                float buf[36];
                #pragma unroll
                for (int i = 0; i < 9; ++i) {
                    f32x4 v = *reinterpret_cast<const f32x4*>(rrow + 72*g + 36*q + 4*i);
                    buf[4*i+0] = v.x; buf[4*i+1] = v.y; buf[4*i+2] = v.z; buf[4*i+3] = v.w;
                }

                #pragma unroll
                for (int l = 0; l < 4; ++l) {
                    const int j  = 8 * g + 4 * q + l;
                    const int pj = PAR[j];
                    const float* L = buf + 9 * l;

                    if (j == 0) {
                        #pragma unroll
                        for (int k = 0; k < 9; ++k) Rg[0][k] = L[k];
                        tg[0][0] = Pg[0]; tg[0][1] = Pg[1]; tg[0][2] = Pg[2];
                    } else {
                        float pxp, pyp, pzp;
                        if (pj >= 8 * g) {
                            const int lp = 3 * pj - 24 * g;
                            pxp = Pg[lp]; pyp = Pg[lp+1]; pzp = Pg[lp+2];
                        } else if (g == 1) {
                            const int ci = 3 * (pj - 5);
                            pxp = carry1[ci]; pyp = carry1[ci+1]; pzp = carry1[ci+2];
                        } else {
                            const int ci = 3 * (pj - 13);
                            pxp = carry2[ci]; pyp = carry2[ci+1]; pzp = carry2[ci+2];
                        }
                        const int lj = 3 * j - 24 * g;
                        float rel[3] = { Pg[lj] - pxp, Pg[lj+1] - pyp, Pg[lj+2] - pzp };
                        #pragma unroll
                        for (int r = 0; r < 3; ++r) {
                            #pragma unroll
                            for (int c = 0; c < 3; ++c) {
                                Rg[j][3*r+c] = Rg[pj][3*r+0] * L[0+c]
                                             + Rg[pj][3*r+1] * L[3+c]
                                             + Rg[pj][3*r+2] * L[6+c];
                            }
                            tg[j][r] = Rg[pj][3*r+0] * rel[0]
                                     + Rg[pj][3*r+1] * rel[1]
                                     + Rg[pj][3*r+2] * rel[2]
                                     + tg[pj][r];
                        }
                    }
                }

                // ---- stage as two 2-joint phases ----
                #pragma unroll
                for (int hp = 0; hp < 2; ++hp) {
                    const int p = 4 * g + 2 * q + hp;      // phase index (static)
                    f32x4* B = &lds[(p & 1) * NF4 + lane * STR];
                    #pragma unroll
                    for (int jj = 0; jj < 2; ++jj) {
                        const int j  = 8 * g + 4 * q + 2 * hp + jj;
                        const int lj = 3 * j - 24 * g;
                        const float px = Pg[lj], py = Pg[lj+1], pz = Pg[lj+2];
                        #pragma unroll
                        for (int r = 0; r < 3; ++r) {
                            const float ib = Rg[j][3*r]*px + Rg[j][3*r+1]*py
                                           + Rg[j][3*r+2]*pz;
                            B[jj*4 + r] = f32x4{Rg[j][3*r], Rg[j][3*r+1],
                                                Rg[j][3*r+2], tg[j][r] - ib};
                        }
                        B[jj*4 + 3] = f32x4{0.f, 0.f, 0.f, 1.f};
                    }
                    sync_lds();
                }
            }

            if (g == 0) {
                #pragma unroll
                for (int k = 0; k < 9; ++k) carry1[k] = Pg[15 + k];
            } else if (g == 1) {
                #pragma unroll
                for (int k = 0; k < 6; ++k) carry2[k] = Pg[15 + k];
            }
        }

        // ---- oP phases 12,13: 12 joints each (36 floats = 9 f4) ----
        #pragma unroll
        for (int ph = 0; ph < 2; ++ph) {
            const int p = 12 + ph;
            f32x4* B = &lds[(p & 1) * NF4 + lane * STR];
            #pragma unroll
            for (int i = 0; i < 9; ++i) {
                float vals[4];
                #pragma unroll
                for (int k = 0; k < 4; ++k) {
                    int e = 36 * ph + 4 * i + k;          // 0..71, static
                    vals[k] = tg[e / 3][e % 3];
                }
                B[i] = f32x4{vals[0], vals[1], vals[2], vals[3]};
            }
            sync_lds();
        }
    } else {
        // ================= store wave =================
        // oT phases: 12 x {wait ready; 8 ds_read f4; 8 nt stores}
        #pragma unroll
        for (int p = 0; p < 12; ++p) {
            sync_lds();
            const f32x4* B = &lds[(p & 1) * NF4];
            float* gp = outT + (size_t)b0 * 384 + p * 32;   // j0 = 2p -> 32 floats
            #pragma unroll
            for (int i = 0; i < 8; ++i) {
                int f = lane + 64 * i;          // 512 f4 = 64 rows x 8
                int row = f >> 3, col = f & 7;
                f32x4 v = B[row * STR + col];
                __builtin_nontemporal_store(
                    v, reinterpret_cast<f32x4*>(gp + (size_t)row * 384 + col * 4));
            }
        }
        // oP phases: 2 x {wait; 9 ds_read f4; 9 nt stores}
        #pragma unroll
        for (int ph = 0; ph < 2; ++ph) {
            const int p = 12 + ph;
            sync_lds();
            const f32x4* B = &lds[(p & 1) * NF4];
            float* gp = outP + (size_t)b0 * 72 + ph * 36;
            #pragma unroll
            for (int i = 0; i < 9; ++i) {
                int f = lane + 64 * i;          // 576 f4 = 64 rows x 9
                int row = f / 9, col = f % 9;
                f32x4 v = B[row * STR + col];
                __builtin_nontemporal_store(
                    v, reinterpret_cast<f32x4*>(gp + (size_t)row * 72 + col * 4));
            }
        }
    }
}

extern "C" void kernel_launch(void* const* d_in, const int* in_sizes, int n_in,
                              void* d_out, int out_size, void* d_ws, size_t ws_size,
                              hipStream_t stream) {
    const float* rot = (const float*)d_in[0];
    const float* pos = (const float*)d_in[1];
    float* outT = (float*)d_out;
    float* outP = outT + (size_t)NB * NJ * 16;
    dim3 grid(NB / BPB), block(BLK);
    hipLaunchKernelGGL(pose_kernel, grid, block, 0, stream, rot, pos, outT, outP);
}

// Round 21
// 66.594 us; speedup vs baseline: 1.5674x; 1.5674x over previous
//
#include <hip/hip_runtime.h>

namespace {
constexpr int NB  = 131072;
constexpr int NJ  = 24;
constexpr int PAR[NJ] = {0,0,0,0,1,2,3,4,5,6,7,8,9,9,9,12,13,14,16,17,18,19,20,21};
constexpr int BLK = 64;         // one wave per block; batches per block
constexpr int SOT = 68;         // LDS row stride (floats) oT staging (64 data + 4 pad)
constexpr int SPO = 76;         // LDS row stride (floats) oP staging (72 data + 4 pad)
constexpr int LDSF = BLK * SPO; // 19456 B -> 8 blocks/CU
}

typedef float f32x4 __attribute__((ext_vector_type(4)));

// CHAMPION (round 8 / re-pinned round 16: 66.6us): single-wave blocks, ZERO
// barriers, direct per-lane input loads (fine-grained dependency chains beat
// coarse LDS staging — r9), LDS only for output transposes, nontemporal
// stores (+38% vs plain, r12 A/B). 8 waves/CU (grid-capped by problem shape;
// finer lanes-per-batch decompositions measured worse — r13/r14/r15; manual
// scheduling null — r11/r17; producer-consumer waves worse — r20).
__global__ __launch_bounds__(BLK) void pose_kernel(
    const float* __restrict__ rot,
    const float* __restrict__ pos,
    float* __restrict__ outT,
    float* __restrict__ outP)
{
    __shared__ __align__(16) float lds[LDSF];
    const int t  = threadIdx.x;   // 0..63, lane == batch within block
    const int b0 = blockIdx.x * BLK;

    const float* prow = pos + (size_t)(b0 + t) * 72;   // this thread's pos row
    const float* rrow = rot + (size_t)(b0 + t) * 216;  // this thread's rot row

    float Rg[NJ][9];
    float tg[NJ][3];
    float carry1[9];   // P of joints 5,6,7   (needed by group 1)
    float carry2[6];   // P of joints 13,14   (needed by group 2)

    #pragma unroll
    for (int g = 0; g < 3; ++g) {
        // ---- group-local positions: joints 8g..8g+7 = floats [24g, 24g+24) ----
        float Pg[24];
        #pragma unroll
        for (int i = 0; i < 6; ++i) {
            f32x4 v = *reinterpret_cast<const f32x4*>(prow + 24 * g + 4 * i);
            Pg[4*i+0] = v.x; Pg[4*i+1] = v.y; Pg[4*i+2] = v.z; Pg[4*i+3] = v.w;
        }

        #pragma unroll
        for (int q = 0; q < 2; ++q) {           // quad = 4 joints
            // ---- direct rot loads: floats [72g+36q, +36) of this row ----
            float buf[36];
            #pragma unroll
            for (int i = 0; i < 9; ++i) {
                f32x4 v = *reinterpret_cast<const f32x4*>(rrow + 72 * g + 36 * q + 4 * i);
                buf[4*i+0] = v.x; buf[4*i+1] = v.y; buf[4*i+2] = v.z; buf[4*i+3] = v.w;
            }

            // ---- compute 4 joints (parent always < j; all indices static) ----
            #pragma unroll
            for (int l = 0; l < 4; ++l) {
                const int j  = 8 * g + 4 * q + l;
                const int pj = PAR[j];
                float L[9];
                #pragma unroll
                for (int k = 0; k < 9; ++k) L[k] = buf[9 * (4 * q + l) - 36 * q + k];

                if (j == 0) {
                    #pragma unroll
                    for (int k = 0; k < 9; ++k) Rg[0][k] = L[k];
                    tg[0][0] = Pg[0]; tg[0][1] = Pg[1]; tg[0][2] = Pg[2];
                } else {
                    float pxp, pyp, pzp;
                    if (pj >= 8 * g) {                 // parent in this group
                        const int lp = 3 * pj - 24 * g;
                        pxp = Pg[lp]; pyp = Pg[lp+1]; pzp = Pg[lp+2];
                    } else if (g == 1) {               // parent in {5,6,7}
                        const int ci = 3 * (pj - 5);
                        pxp = carry1[ci]; pyp = carry1[ci+1]; pzp = carry1[ci+2];
                    } else {                           // g==2, parent in {13,14}
                        const int ci = 3 * (pj - 13);
                        pxp = carry2[ci]; pyp = carry2[ci+1]; pzp = carry2[ci+2];
                    }
                    const int lj = 3 * j - 24 * g;
                    float rel[3] = { Pg[lj] - pxp, Pg[lj+1] - pyp, Pg[lj+2] - pzp };
                    #pragma unroll
                    for (int r = 0; r < 3; ++r) {
                        #pragma unroll
                        for (int c = 0; c < 3; ++c) {
                            Rg[j][3*r+c] = Rg[pj][3*r+0] * L[0+c]
                                         + Rg[pj][3*r+1] * L[3+c]
                                         + Rg[pj][3*r+2] * L[6+c];
                        }
                        tg[j][r] = Rg[pj][3*r+0] * rel[0]
                                 + Rg[pj][3*r+1] * rel[1]
                                 + Rg[pj][3*r+2] * rel[2]
                                 + tg[pj][r];
                    }
                }
            }

            // ---- oT: stage this quad (64 floats/row) then coalesced nt write ----
            #pragma unroll
            for (int l = 0; l < 4; ++l) {
                const int j  = 8 * g + 4 * q + l;
                const int lj = 3 * j - 24 * g;
                float px = Pg[lj], py = Pg[lj+1], pz = Pg[lj+2];
                #pragma unroll
                for (int r = 0; r < 3; ++r) {
                    float ib = Rg[j][3*r]*px + Rg[j][3*r+1]*py + Rg[j][3*r+2]*pz;
                    *reinterpret_cast<f32x4*>(&lds[t * SOT + (l*4 + r) * 4]) =
                        f32x4{Rg[j][3*r], Rg[j][3*r+1], Rg[j][3*r+2], tg[j][r] - ib};
                }
                *reinterpret_cast<f32x4*>(&lds[t * SOT + (l*4 + 3) * 4]) =
                    f32x4{0.f, 0.f, 0.f, 1.f};
            }
            {
                float* gp = outT + (size_t)b0 * 384 + (8 * g + 4 * q) * 16;
                #pragma unroll
                for (int i = 0; i < 16; ++i) {
                    int f = t + BLK * i;          // 1024 f4 = 64 rows x 16
                    int row = f >> 4, col = f & 15;
                    f32x4 v = *reinterpret_cast<const f32x4*>(&lds[row * SOT + col * 4]);
                    __builtin_nontemporal_store(
                        v, reinterpret_cast<f32x4*>(gp + (size_t)row * 384 + col * 4));
                }
            }
        }

        // ---- save cross-group parent positions (all static) ----
        if (g == 0) {
            #pragma unroll
            for (int k = 0; k < 9; ++k) carry1[k] = Pg[15 + k];   // joints 5,6,7
        } else if (g == 1) {
            #pragma unroll
            for (int k = 0; k < 6; ++k) carry2[k] = Pg[15 + k];   // joints 13,14
        }
    }

    // ---- oP: stage all 24 translations (72 floats/row), coalesced nt write ----
    #pragma unroll
    for (int i = 0; i < 18; ++i) {
        float vals[4];
        #pragma unroll
        for (int k = 0; k < 4; ++k) {
            int e = 4*i + k;                  // 0..71, static
            vals[k] = tg[e / 3][e % 3];
        }
        *reinterpret_cast<f32x4*>(&lds[t * SPO + i * 4]) =
            f32x4{vals[0], vals[1], vals[2], vals[3]};
    }
    {
        float* gp = outP + (size_t)b0 * 72;
        #pragma unroll
        for (int i = 0; i < 18; ++i) {
            int f = t + BLK * i;              // 1152 f4 = 64 rows x 18
            int row = f / 18, col = f % 18;
            f32x4 v = *reinterpret_cast<const f32x4*>(&lds[row * SPO + col * 4]);
            __builtin_nontemporal_store(
                v, reinterpret_cast<f32x4*>(gp + (size_t)row * 72 + col * 4));
        }
    }
}

extern "C" void kernel_launch(void* const* d_in, const int* in_sizes, int n_in,
                              void* d_out, int out_size, void* d_ws, size_t ws_size,
                              hipStream_t stream) {
    const float* rot = (const float*)d_in[0];
    const float* pos = (const float*)d_in[1];
    float* outT = (float*)d_out;
    float* outP = outT + (size_t)NB * NJ * 16;
    dim3 grid(NB / BLK), block(BLK);
    hipLaunchKernelGGL(pose_kernel, grid, block, 0, stream, rot, pos, outT, outP);
}